// Round 17
// baseline (127.238 us; speedup 1.0000x reference)
//
#include <hip/hip_runtime.h>
#include <cstdint>
#include <cstddef>

// ---------------------------------------------------------------------------
// SelfAttention block on MI355X (gfx950), bf16 MFMA path, round 16.
//   Base = R15 (124.1 us).  One change: attention K/V tiles use an
//   8B-granularity swizzle (row&15)<<3 and paired ds_read_b64 fragment loads
//   -> 32-row wave reads hit every bank exactly 4x (zero conflicts).
//   Producers (qkv scatter) updated with the same involution.  All sync
//   structure identical to R15.
// ---------------------------------------------------------------------------

typedef short  b16x8  __attribute__((ext_vector_type(8)));    // 8 bf16 (4 VGPRs)
typedef float  f32x4  __attribute__((ext_vector_type(4)));
typedef float  f32x16 __attribute__((ext_vector_type(16)));   // 32x32 MFMA acc

#define AS1 __attribute__((address_space(1)))
#define AS3 __attribute__((address_space(3)))

__device__ __forceinline__ unsigned short f2bf(float f) {   // RNE f32->bf16
    unsigned int u = __builtin_bit_cast(unsigned int, f);
    u += 0x7FFFu + ((u >> 16) & 1u);
    return (unsigned short)(u >> 16);
}

__device__ __forceinline__ unsigned int cvt_pk_bf16(float lo, float hi) {
    unsigned int r;
    asm("v_cvt_pk_bf16_f32 %0, %1, %2" : "=v"(r) : "v"(lo), "v"(hi));
    return r;
}

__device__ __forceinline__ float exp2_fast(float x) {       // 2^x, raw v_exp
    float r;
    asm("v_exp_f32 %0, %1" : "=v"(r) : "v"(x));
    return r;
}

// after swap: a = {a.lo32 | b.lo32}, b = {a.hi32 | b.hi32}
__device__ __forceinline__ void permswap(unsigned &a, unsigned &b) {
    asm volatile("v_permlane32_swap_b32 %0, %1" : "+v"(a), "+v"(b));
}

// ---------------- convert x (f32) -> bf16, tiled+swizzled [rt][kt][128x64] ----------------
__global__ __launch_bounds__(256) void k_cvt_x(const float* __restrict__ x,
                                               unsigned short* __restrict__ xb) {
    int i = blockIdx.x * 256 + threadIdx.x;          // 512K threads x 8 elems
    size_t base = (size_t)i * 8;
    float4 v0 = *(const float4*)(x + base);
    float4 v1 = *(const float4*)(x + base + 4);
    int row = (int)(base >> 10), col = (int)(base & 1023);
    int rt = row >> 7, rr = row & 127, kt = col >> 6, cc = col & 63;
    int e = (rr * 64 + cc) ^ ((rr & 7) << 3);
    unsigned short o[8];
    o[0] = f2bf(v0.x); o[1] = f2bf(v0.y); o[2] = f2bf(v0.z); o[3] = f2bf(v0.w);
    o[4] = f2bf(v1.x); o[5] = f2bf(v1.y); o[6] = f2bf(v1.z); o[7] = f2bf(v1.w);
    *(uint4*)(xb + (size_t)(rt * 16 + kt) * 8192 + e) = *(uint4*)o;
}

// ---------------- transpose+convert W ----------------
// all four: tiled+swizzled [nt][kt][128x64] (row = n&127, col = k&63).
__global__ __launch_bounds__(1024) void k_cvt_w(
    const float* __restrict__ W0, const float* __restrict__ W1,
    const float* __restrict__ W2, const float* __restrict__ W3,
    unsigned short* __restrict__ T0, unsigned short* __restrict__ T1,
    unsigned short* __restrict__ T2, unsigned short* __restrict__ T3) {
    const float* W = blockIdx.z == 0 ? W0 : blockIdx.z == 1 ? W1 : blockIdx.z == 2 ? W2 : W3;
    unsigned short* T = blockIdx.z == 0 ? T0 : blockIdx.z == 1 ? T1 : blockIdx.z == 2 ? T2 : T3;
    __shared__ float tile[32][33];
    int k0 = blockIdx.x * 32, n0 = blockIdx.y * 32;
    int tx = threadIdx.x, ty = threadIdx.y;
    tile[ty][tx] = W[(size_t)(k0 + ty) * 1024 + n0 + tx];
    __syncthreads();
    int n = n0 + ty, k = k0 + tx;
    unsigned short v = f2bf(tile[tx][ty]);
    int r = n & 127, c = k & 63;
    int e = (r * 64 + c) ^ ((r & 7) << 3);
    T[(size_t)((n >> 7) * 16 + (k >> 6)) * 8192 + e] = v;
}

// ---------------- fused QKV GEMM: 128x128 tile, BK=64, 3-buf counted vmcnt (R10) ----------------
__global__ __launch_bounds__(512) void k_gemm_qkv(
    const unsigned short* __restrict__ A, const unsigned short* __restrict__ Bt,
    const float* __restrict__ bq, const float* __restrict__ bk, const float* __restrict__ bv,
    unsigned short* __restrict__ Qb, unsigned short* __restrict__ Kt,
    unsigned short* __restrict__ Vt) {
    __shared__ unsigned short As[3][8192];   // 48 KB
    __shared__ unsigned short Bs[3][8192];   // 48 KB
    const int tid = threadIdx.x, lane = tid & 63, wid = tid >> 6;
    const int m0 = blockIdx.y * 128, n0 = blockIdx.x * 128;
    const int wr = wid >> 2, wc = wid & 3;   // wr 0..1 (64 rows), wc 0..3 (32 cols)
    const int g = lane >> 4, r = lane & 15;
    f32x4 acc[4][2] = {};

    const unsigned short* Abase = A  + (size_t)blockIdx.y * 16 * 8192;
    const unsigned short* Bbase = Bt + (size_t)blockIdx.x * 16 * 8192;

#define GSTAGE(kt, buf) do {                                                              \
        const unsigned short* _a = Abase + (size_t)(kt) * 8192 + tid * 8;                 \
        const unsigned short* _b = Bbase + (size_t)(kt) * 8192 + tid * 8;                 \
        __builtin_amdgcn_global_load_lds((const AS1 void*)(_a),        (AS3 void*)((char*)As[buf] + tid * 16),        16, 0, 0); \
        __builtin_amdgcn_global_load_lds((const AS1 void*)(_a + 4096), (AS3 void*)((char*)As[buf] + 8192 + tid * 16), 16, 0, 0); \
        __builtin_amdgcn_global_load_lds((const AS1 void*)(_b),        (AS3 void*)((char*)Bs[buf] + tid * 16),        16, 0, 0); \
        __builtin_amdgcn_global_load_lds((const AS1 void*)(_b + 4096), (AS3 void*)((char*)Bs[buf] + 8192 + tid * 16), 16, 0, 0); \
    } while (0)

    GSTAGE(0, 0);
    GSTAGE(1, 1);
    asm volatile("s_waitcnt vmcnt(4)" ::: "memory");   // tile0 landed; tile1 in flight
    __builtin_amdgcn_s_barrier();
    __builtin_amdgcn_sched_barrier(0);

    for (int kt = 0; kt < 16; ++kt) {
        const unsigned short* Ac = As[kt % 3];
        const unsigned short* Bc = Bs[kt % 3];
        if (kt < 14) GSTAGE(kt + 2, (kt + 2) % 3);     // distance-2 prefetch
#pragma unroll
        for (int kk = 0; kk < 2; ++kk) {
            b16x8 af[4], bfr[2];
#pragma unroll
            for (int mi = 0; mi < 4; ++mi) {
                int row = wr * 64 + mi * 16 + r;
                int e = (row * 64 + kk * 32 + g * 8) ^ ((row & 7) << 3);
                af[mi] = __builtin_bit_cast(b16x8, *(const uint4*)(Ac + e));
            }
#pragma unroll
            for (int ni = 0; ni < 2; ++ni) {
                int row = wc * 32 + ni * 16 + r;
                int e = (row * 64 + kk * 32 + g * 8) ^ ((row & 7) << 3);
                bfr[ni] = __builtin_bit_cast(b16x8, *(const uint4*)(Bc + e));
            }
#pragma unroll
            for (int mi = 0; mi < 4; ++mi)
#pragma unroll
                for (int ni = 0; ni < 2; ++ni)
                    acc[mi][ni] = __builtin_amdgcn_mfma_f32_16x16x32_bf16(af[mi], bfr[ni], acc[mi][ni], 0, 0, 0);
        }
        asm volatile("s_waitcnt lgkmcnt(0)" ::: "memory");   // my ds_reads retired
        if (kt < 15) {
            if (kt < 14) asm volatile("s_waitcnt vmcnt(4)" ::: "memory");  // next tile landed
            else         asm volatile("s_waitcnt vmcnt(0)" ::: "memory");  // last tile: drain
            __builtin_amdgcn_s_barrier();
            __builtin_amdgcn_sched_barrier(0);
        }
    }
#undef GSTAGE

    for (int ni = 0; ni < 2; ++ni) {
        int col = n0 + wc * 32 + ni * 16 + r;           // [0, 3072)
        int which = col >> 10, c = col & 1023;
        const float* bp = which == 0 ? bq : which == 1 ? bk : bv;
        float bvv = bp[c];
        int h = c >> 6, hd = c & 63;
        for (int mi = 0; mi < 4; ++mi)
            for (int j = 0; j < 4; ++j) {
                int row = m0 + wr * 64 + mi * 16 + g * 4 + j;
                float v = acc[mi][ni][j] + bvv;
                int b = row >> 11, s = row & 2047;
                size_t bh = (size_t)(b * 16 + h);
                if (which == 0) {
                    Qb[(bh * 2048 + s) * 64 + hd] = f2bf(v * 0.180336881f);  // 0.125*log2e
                } else if (which == 1) {
                    int tt = s >> 6, kr = s & 63;
                    // 8B-granularity swizzle (matches attn b64 reads)
                    Kt[(bh * 32 + tt) * 4096 + ((kr * 64 + hd) ^ ((kr & 15) << 2))] = f2bf(v);
                } else {
                    int tt = s >> 6, cc = s & 63;
                    Vt[(bh * 32 + tt) * 4096 + ((hd * 64 + cc) ^ ((hd & 15) << 2))] = f2bf(v);
                }
            }
    }
}

// ---------------- proj GEMM: 128x128 tile, BK=64, 3-buf counted vmcnt (R15) ----------------
__global__ __launch_bounds__(512) void k_gemm_proj(
    const unsigned short* __restrict__ A, const unsigned short* __restrict__ Bt,
    const float* __restrict__ bias, const float* __restrict__ x,
    float* __restrict__ out) {
    __shared__ unsigned short As[3][8192];   // 48 KB
    __shared__ unsigned short Bs[3][8192];   // 48 KB
    const int tid = threadIdx.x, lane = tid & 63, wid = tid >> 6;
    const int m0 = blockIdx.y * 128, n0 = blockIdx.x * 128;
    const int wr = wid >> 2, wc = wid & 3;
    const int g = lane >> 4, r = lane & 15;
    f32x4 acc[4][2] = {};

    const unsigned short* Abase = A  + (size_t)blockIdx.y * 16 * 8192;
    const unsigned short* Bbase = Bt + (size_t)blockIdx.x * 16 * 8192;

#define PSTAGE(kt, buf) do {                                                              \
        const unsigned short* _a = Abase + (size_t)(kt) * 8192 + tid * 8;                 \
        const unsigned short* _b = Bbase + (size_t)(kt) * 8192 + tid * 8;                 \
        __builtin_amdgcn_global_load_lds((const AS1 void*)(_a),        (AS3 void*)((char*)As[buf] + tid * 16),        16, 0, 0); \
        __builtin_amdgcn_global_load_lds((const AS1 void*)(_a + 4096), (AS3 void*)((char*)As[buf] + 8192 + tid * 16), 16, 0, 0); \
        __builtin_amdgcn_global_load_lds((const AS1 void*)(_b),        (AS3 void*)((char*)Bs[buf] + tid * 16),        16, 0, 0); \
        __builtin_amdgcn_global_load_lds((const AS1 void*)(_b + 4096), (AS3 void*)((char*)Bs[buf] + 8192 + tid * 16), 16, 0, 0); \
    } while (0)

    PSTAGE(0, 0);
    PSTAGE(1, 1);
    asm volatile("s_waitcnt vmcnt(4)" ::: "memory");
    __builtin_amdgcn_s_barrier();
    __builtin_amdgcn_sched_barrier(0);

    for (int kt = 0; kt < 16; ++kt) {
        const unsigned short* Ac = As[kt % 3];
        const unsigned short* Bc = Bs[kt % 3];
        if (kt < 14) PSTAGE(kt + 2, (kt + 2) % 3);
#pragma unroll
        for (int kk = 0; kk < 2; ++kk) {
            b16x8 af[4], bfr[2];
#pragma unroll
            for (int mi = 0; mi < 4; ++mi) {
                int row = wr * 64 + mi * 16 + r;
                int e = (row * 64 + kk * 32 + g * 8) ^ ((row & 7) << 3);
                af[mi] = __builtin_bit_cast(b16x8, *(const uint4*)(Ac + e));
            }
#pragma unroll
            for (int ni = 0; ni < 2; ++ni) {
                int row = wc * 32 + ni * 16 + r;
                int e = (row * 64 + kk * 32 + g * 8) ^ ((row & 7) << 3);
                bfr[ni] = __builtin_bit_cast(b16x8, *(const uint4*)(Bc + e));
            }
#pragma unroll
            for (int mi = 0; mi < 4; ++mi)
#pragma unroll
                for (int ni = 0; ni < 2; ++ni)
                    acc[mi][ni] = __builtin_amdgcn_mfma_f32_16x16x32_bf16(af[mi], bfr[ni], acc[mi][ni], 0, 0, 0);
        }
        asm volatile("s_waitcnt lgkmcnt(0)" ::: "memory");
        if (kt < 15) {
            if (kt < 14) asm volatile("s_waitcnt vmcnt(4)" ::: "memory");
            else         asm volatile("s_waitcnt vmcnt(0)" ::: "memory");
            __builtin_amdgcn_s_barrier();
            __builtin_amdgcn_sched_barrier(0);
        }
    }
#undef PSTAGE

    for (int ni = 0; ni < 2; ++ni) {
        int col = n0 + wc * 32 + ni * 16 + r;
        float bv = bias[col];
        for (int mi = 0; mi < 4; ++mi)
            for (int j = 0; j < 4; ++j) {
                int row = m0 + wr * 64 + mi * 16 + g * 4 + j;
                size_t off = (size_t)row * 1024 + col;
                out[off] = acc[mi][ni][j] + bv + x[off];   // residual fused
            }
    }
}

// ---------------- flash attention: split-KV, fixed-base softmax, b64 K/V reads ----------------
// Kt/Vt: [bh][32][64x64] tiles, 8B-granularity swizzle (row&15)<<3 bytes.
// ctx written tiled+swizzled [rt][kt][128x64] for the proj GEMM.
__device__ __forceinline__ b16x8 ld_kv64(const char* base, int row, int off) {
    int sw = (row & 15) << 3;
    uint2 a = *(const uint2*)(base + row * 128 + ((off)     ^ sw));
    uint2 b = *(const uint2*)(base + row * 128 + ((off + 8) ^ sw));
    uint4 u; u.x = a.x; u.y = a.y; u.z = b.x; u.w = b.y;
    return __builtin_bit_cast(b16x8, u);
}

__global__ __launch_bounds__(512, 4) void k_attn(const unsigned short* __restrict__ Qb,
                                                 const unsigned short* __restrict__ Kt,
                                                 const unsigned short* __restrict__ Vt,
                                                 unsigned short* __restrict__ ctx) {
    __shared__ unsigned short Ks[2][2][4096];   // [group][dbuf] 32 KB
    __shared__ unsigned short Vs[2][2][4096];   // 32 KB
    __shared__ float lsh[4][64];                // 1 KB (group1 l)
    const int tid = threadIdx.x, lane = tid & 63, w = tid >> 6;   // w in 0..7
    const int q32 = lane & 31, hi = lane >> 5;
    const int wq = w & 3, grp = w >> 2;
    const int lt = wq * 64 + lane;              // 0..255 within group

    int bid = blockIdx.x;
    int xcd = bid & 7, idx = bid >> 3;
    int bh = xcd * 4 + (idx & 3);               // 4 heads/XCD -> K/V L2-resident
    int q0 = (idx >> 2) * 128;
    const int b = bh >> 4, h = bh & 15;

    const unsigned short* qrow = Qb + ((size_t)bh * 2048 + q0 + wq * 32 + q32) * 64 + hi * 8;
    b16x8 qf[4];
#pragma unroll
    for (int ds = 0; ds < 4; ++ds)
        qf[ds] = __builtin_bit_cast(b16x8, *(const uint4*)(qrow + ds * 16));

    const unsigned short* Kg = Kt + (size_t)bh * 32 * 4096;
    const unsigned short* Vg = Vt + (size_t)bh * 32 * 4096;
    const int ktbase = grp * 16;

#define STAGE(i, buf) do {                                                                \
        const unsigned short* _ks = Kg + (size_t)(ktbase + (i)) * 4096 + lt * 8;          \
        const unsigned short* _vs = Vg + (size_t)(ktbase + (i)) * 4096 + lt * 8;          \
        __builtin_amdgcn_global_load_lds((const AS1 void*)_ks,          (AS3 void*)((char*)Ks[grp][buf] + lt * 16),        16, 0, 0); \
        __builtin_amdgcn_global_load_lds((const AS1 void*)(_ks + 2048), (AS3 void*)((char*)Ks[grp][buf] + 4096 + lt * 16), 16, 0, 0); \
        __builtin_amdgcn_global_load_lds((const AS1 void*)_vs,          (AS3 void*)((char*)Vs[grp][buf] + lt * 16),        16, 0, 0); \
        __builtin_amdgcn_global_load_lds((const AS1 void*)(_vs + 2048), (AS3 void*)((char*)Vs[grp][buf] + 4096 + lt * 16), 16, 0, 0); \
    } while (0)

    float lpart = 0.f;
    f32x16 oacc[2] = {};

    STAGE(0, 0);
    __syncthreads();

    for (int i = 0; i < 16; ++i) {
        const int cur = i & 1;
        if (i < 15) STAGE(i + 1, cur ^ 1);      // async prefetch, drained at barrier

        f32x16 sacc[2] = {};
#pragma unroll
        for (int ds = 0; ds < 4; ++ds) {
            b16x8 kf0 = ld_kv64((const char*)Ks[grp][cur], q32,      ds * 32 + hi * 16);
            b16x8 kf1 = ld_kv64((const char*)Ks[grp][cur], 32 + q32, ds * 32 + hi * 16);
            sacc[0] = __builtin_amdgcn_mfma_f32_32x32x16_bf16(kf0, qf[ds], sacc[0], 0, 0, 0);
            sacc[1] = __builtin_amdgcn_mfma_f32_32x32x16_bf16(kf1, qf[ds], sacc[1], 0, 0, 0);
        }

        // fixed-base softmax: P = 2^s (scores bounded; shift-invariant; l divides out)
        float pb[2][16];
#pragma unroll
        for (int kb = 0; kb < 2; ++kb)
#pragma unroll
            for (int reg = 0; reg < 16; ++reg)
                pb[kb][reg] = exp2_fast(sacc[kb][reg]);
        {   // balanced-tree sum
            float t0 = (pb[0][0]  + pb[0][1])  + (pb[0][2]  + pb[0][3]);
            float t1 = (pb[0][4]  + pb[0][5])  + (pb[0][6]  + pb[0][7]);
            float t2 = (pb[0][8]  + pb[0][9])  + (pb[0][10] + pb[0][11]);
            float t3 = (pb[0][12] + pb[0][13]) + (pb[0][14] + pb[0][15]);
            float t4 = (pb[1][0]  + pb[1][1])  + (pb[1][2]  + pb[1][3]);
            float t5 = (pb[1][4]  + pb[1][5])  + (pb[1][6]  + pb[1][7]);
            float t6 = (pb[1][8]  + pb[1][9])  + (pb[1][10] + pb[1][11]);
            float t7 = (pb[1][12] + pb[1][13]) + (pb[1][14] + pb[1][15]);
            lpart += ((t0 + t1) + (t2 + t3)) + ((t4 + t5) + (t6 + t7));
        }
        unsigned wv[2][4][2];
#pragma unroll
        for (int kb = 0; kb < 2; ++kb)
#pragma unroll
            for (int rg = 0; rg < 4; ++rg) {
                wv[kb][rg][0] = cvt_pk_bf16(pb[kb][rg * 4 + 0], pb[kb][rg * 4 + 1]);
                wv[kb][rg][1] = cvt_pk_bf16(pb[kb][rg * 4 + 2], pb[kb][rg * 4 + 3]);
            }
        b16x8 pa[4];
#pragma unroll
        for (int ks = 0; ks < 4; ++ks) {
            int kb = ks >> 1, rg0 = (ks & 1) * 2;
            unsigned u0 = wv[kb][rg0][0], u2 = wv[kb][rg0 + 1][0];
            permswap(u0, u2);
            unsigned u1 = wv[kb][rg0][1], u3 = wv[kb][rg0 + 1][1];
            permswap(u1, u3);
            uint4 uu; uu.x = u0; uu.y = u1; uu.z = u2; uu.w = u3;
            pa[ks] = __builtin_bit_cast(b16x8, uu);
        }
#pragma unroll
        for (int ks = 0; ks < 4; ++ks) {
            b16x8 vf0 = ld_kv64((const char*)Vs[grp][cur], q32,      ks * 32 + hi * 16);
            b16x8 vf1 = ld_kv64((const char*)Vs[grp][cur], 32 + q32, ks * 32 + hi * 16);
            oacc[0] = __builtin_amdgcn_mfma_f32_32x32x16_bf16(pa[ks], vf0, oacc[0], 0, 0, 0);
            oacc[1] = __builtin_amdgcn_mfma_f32_32x32x16_bf16(pa[ks], vf1, oacc[1], 0, 0, 0);
        }
        __syncthreads();
    }

    {
        unsigned a = __builtin_bit_cast(unsigned, lpart), bb = a;
        permswap(a, bb);
        lpart = __builtin_bit_cast(float, a) + __builtin_bit_cast(float, bb);
    }

    float* s0 = (float*)Ks[1];
    float* s1 = (float*)Vs[1];
    if (grp == 1) {
        int base = (wq * 64 + lane) * 16;
#pragma unroll
        for (int reg = 0; reg < 16; ++reg) {
            s0[base + reg] = oacc[0][reg];
            s1[base + reg] = oacc[1][reg];
        }
        lsh[wq][lane] = lpart;
    }
    __syncthreads();
    if (grp == 0) {
        float l = lpart + lsh[wq][lane];
        float inv = 1.f / l;
        int base = (wq * 64 + lane) * 16;
#pragma unroll
        for (int reg = 0; reg < 16; ++reg) {
            int qr = (reg & 3) + 8 * (reg >> 2) + 4 * hi;
            float iv = __shfl(inv, qr, 64);
            float o0 = (oacc[0][reg] + s0[base + reg]) * iv;
            float o1 = (oacc[1][reg] + s1[base + reg]) * iv;
            // ctx tiled+swizzled [rt][kt=h][128x64]
            int row = b * 2048 + q0 + wq * 32 + qr;
            int rt = row >> 7, rr = row & 127;
            size_t tbase = (size_t)(rt * 16 + h) * 8192;
            ctx[tbase + ((rr * 64 + q32)      ^ ((rr & 7) << 3))] = f2bf(o0);
            ctx[tbase + ((rr * 64 + q32 + 32) ^ ((rr & 7) << 3))] = f2bf(o1);
        }
    }
#undef STAGE
}

// ---------------- LayerNorm (residual already fused into proj): one wave per row ----------------
__global__ __launch_bounds__(256) void k_ln(const float* __restrict__ yin,
                                            const float* __restrict__ gamma,
                                            const float* __restrict__ beta,
                                            float* __restrict__ out) {
    int t = threadIdx.x, lane = t & 63, w = t >> 6;
    int row = blockIdx.x * 4 + w;
    const float4* yr = (const float4*)(yin + (size_t)row * 1024);
    float4 y[4];
    float s = 0.f, ss = 0.f;
#pragma unroll
    for (int i = 0; i < 4; ++i) {
        float4 yy = yr[lane + i * 64];
        y[i] = yy;
        s  += yy.x + yy.y + yy.z + yy.w;
        ss += yy.x * yy.x + yy.y * yy.y + yy.z * yy.z + yy.w * yy.w;
    }
#pragma unroll
    for (int o = 32; o > 0; o >>= 1) {
        s  += __shfl_xor(s,  o, 64);
        ss += __shfl_xor(ss, o, 64);
    }
    float mu  = s * (1.f / 1024.f);
    float var = ss * (1.f / 1024.f) - mu * mu;
    float inv = rsqrtf(var + 1e-5f);
    float4* outr = (float4*)(out + (size_t)row * 1024);
    const float4* gr = (const float4*)gamma;
    const float4* br = (const float4*)beta;
#pragma unroll
    for (int i = 0; i < 4; ++i) {
        float4 g4 = gr[lane + i * 64], b4 = br[lane + i * 64];
        float4 o4;
        o4.x = (y[i].x - mu) * inv * g4.x + b4.x;
        o4.y = (y[i].y - mu) * inv * g4.y + b4.y;
        o4.z = (y[i].z - mu) * inv * g4.z + b4.z;
        o4.w = (y[i].w - mu) * inv * g4.w + b4.w;
        outr[lane + i * 64] = o4;
    }
}

// ---------------------------------------------------------------------------
extern "C" void kernel_launch(void* const* d_in, const int* in_sizes, int n_in,
                              void* d_out, int out_size, void* d_ws, size_t ws_size,
                              hipStream_t stream) {
    const float* x  = (const float*)d_in[0];
    const float* Wq = (const float*)d_in[1];
    const float* bq = (const float*)d_in[2];
    const float* Wk = (const float*)d_in[3];
    const float* bk = (const float*)d_in[4];
    const float* Wv = (const float*)d_in[5];
    const float* bv = (const float*)d_in[6];
    const float* Wo = (const float*)d_in[7];
    const float* bo = (const float*)d_in[8];
    const float* gamma = (const float*)d_in[9];
    const float* beta  = (const float*)d_in[10];

    char* ws = (char*)d_ws;
    const size_t MB = 1u << 20;
    unsigned short* xbf   = (unsigned short*)(ws);            // 8 MiB tiled; reused as ctx (tiled)
    unsigned short* Wqkvt = (unsigned short*)(ws + 8 * MB);   // 6 MiB tiled [24][16][8192]
    unsigned short* Wot   = (unsigned short*)(ws + 14 * MB);  // 2 MiB tiled [8][16][8192]
    unsigned short* Qb    = (unsigned short*)(ws + 16 * MB);  // 8 MiB
    unsigned short* Kt    = (unsigned short*)(ws + 24 * MB);  // 8 MiB (swz tiles)
    unsigned short* Vt    = (unsigned short*)(ws + 32 * MB);  // 8 MiB (swz tiles)
    float* proj = (float*)(ws + 16 * MB);                     // 16 MiB, overlays Qb+Kt (dead by then)
    unsigned short* ctx = xbf;                                // overlays xbf (dead after qkv)

    k_cvt_x<<<2048, 256, 0, stream>>>(x, xbf);
    k_cvt_w<<<dim3(32, 32, 4), dim3(32, 32), 0, stream>>>(
        Wq, Wk, Wv, Wo, Wqkvt, Wqkvt + 1024 * 1024, Wqkvt + 2 * 1024 * 1024, Wot);
    k_gemm_qkv<<<dim3(24, 32), 512, 0, stream>>>(xbf, Wqkvt, bq, bk, bv, Qb, Kt, Vt);
    k_attn<<<512, 512, 0, stream>>>(Qb, Kt, Vt, ctx);
    k_gemm_proj<<<dim3(8, 32), 512, 0, stream>>>(ctx, Wot, bo, x, proj);
    k_ln<<<1024, 256, 0, stream>>>(proj, gamma, beta, (float*)d_out);
}

// Round 18
// 121.061 us; speedup vs baseline: 1.0510x; 1.0510x over previous
//
#include <hip/hip_runtime.h>
#include <cstdint>
#include <cstddef>

// ---------------------------------------------------------------------------
// SelfAttention block on MI355X (gfx950), bf16 MFMA path, round 17.
//   Base = R15 (best validated, 124.1 us).  R16's attn b64-swizzle reverted
//   (conflicts dropped but instruction-issue cost exceeded the win).
//   One new lever: XCD-aware block swizzle on qkv (96 blocks/XCD) and proj
//   (32/XCD) for per-XCD L2 A-panel locality.  Zero sync-structure changes.
// ---------------------------------------------------------------------------

typedef short  b16x8  __attribute__((ext_vector_type(8)));    // 8 bf16 (4 VGPRs)
typedef float  f32x4  __attribute__((ext_vector_type(4)));
typedef float  f32x16 __attribute__((ext_vector_type(16)));   // 32x32 MFMA acc

#define AS1 __attribute__((address_space(1)))
#define AS3 __attribute__((address_space(3)))

__device__ __forceinline__ unsigned short f2bf(float f) {   // RNE f32->bf16
    unsigned int u = __builtin_bit_cast(unsigned int, f);
    u += 0x7FFFu + ((u >> 16) & 1u);
    return (unsigned short)(u >> 16);
}

__device__ __forceinline__ unsigned int cvt_pk_bf16(float lo, float hi) {
    unsigned int r;
    asm("v_cvt_pk_bf16_f32 %0, %1, %2" : "=v"(r) : "v"(lo), "v"(hi));
    return r;
}

__device__ __forceinline__ float exp2_fast(float x) {       // 2^x, raw v_exp
    float r;
    asm("v_exp_f32 %0, %1" : "=v"(r) : "v"(x));
    return r;
}

// after swap: a = {a.lo32 | b.lo32}, b = {a.hi32 | b.hi32}
__device__ __forceinline__ void permswap(unsigned &a, unsigned &b) {
    asm volatile("v_permlane32_swap_b32 %0, %1" : "+v"(a), "+v"(b));
}

// ---------------- convert x (f32) -> bf16, tiled+swizzled [rt][kt][128x64] ----------------
__global__ __launch_bounds__(256) void k_cvt_x(const float* __restrict__ x,
                                               unsigned short* __restrict__ xb) {
    int i = blockIdx.x * 256 + threadIdx.x;          // 512K threads x 8 elems
    size_t base = (size_t)i * 8;
    float4 v0 = *(const float4*)(x + base);
    float4 v1 = *(const float4*)(x + base + 4);
    int row = (int)(base >> 10), col = (int)(base & 1023);
    int rt = row >> 7, rr = row & 127, kt = col >> 6, cc = col & 63;
    int e = (rr * 64 + cc) ^ ((rr & 7) << 3);
    unsigned short o[8];
    o[0] = f2bf(v0.x); o[1] = f2bf(v0.y); o[2] = f2bf(v0.z); o[3] = f2bf(v0.w);
    o[4] = f2bf(v1.x); o[5] = f2bf(v1.y); o[6] = f2bf(v1.z); o[7] = f2bf(v1.w);
    *(uint4*)(xb + (size_t)(rt * 16 + kt) * 8192 + e) = *(uint4*)o;
}

// ---------------- transpose+convert W ----------------
// all four: tiled+swizzled [nt][kt][128x64] (row = n&127, col = k&63).
__global__ __launch_bounds__(1024) void k_cvt_w(
    const float* __restrict__ W0, const float* __restrict__ W1,
    const float* __restrict__ W2, const float* __restrict__ W3,
    unsigned short* __restrict__ T0, unsigned short* __restrict__ T1,
    unsigned short* __restrict__ T2, unsigned short* __restrict__ T3) {
    const float* W = blockIdx.z == 0 ? W0 : blockIdx.z == 1 ? W1 : blockIdx.z == 2 ? W2 : W3;
    unsigned short* T = blockIdx.z == 0 ? T0 : blockIdx.z == 1 ? T1 : blockIdx.z == 2 ? T2 : T3;
    __shared__ float tile[32][33];
    int k0 = blockIdx.x * 32, n0 = blockIdx.y * 32;
    int tx = threadIdx.x, ty = threadIdx.y;
    tile[ty][tx] = W[(size_t)(k0 + ty) * 1024 + n0 + tx];
    __syncthreads();
    int n = n0 + ty, k = k0 + tx;
    unsigned short v = f2bf(tile[tx][ty]);
    int r = n & 127, c = k & 63;
    int e = (r * 64 + c) ^ ((r & 7) << 3);
    T[(size_t)((n >> 7) * 16 + (k >> 6)) * 8192 + e] = v;
}

// ---------------- fused QKV GEMM: 128x128 tile, BK=64, 3-buf counted vmcnt ----------------
// grid 768 linear, XCD-swizzled: each XCD owns 4 consecutive m-panels x all n.
__global__ __launch_bounds__(512) void k_gemm_qkv(
    const unsigned short* __restrict__ A, const unsigned short* __restrict__ Bt,
    const float* __restrict__ bq, const float* __restrict__ bk, const float* __restrict__ bv,
    unsigned short* __restrict__ Qb, unsigned short* __restrict__ Kt,
    unsigned short* __restrict__ Vt) {
    __shared__ unsigned short As[3][8192];   // 48 KB
    __shared__ unsigned short Bs[3][8192];   // 48 KB
    const int tid = threadIdx.x, lane = tid & 63, wid = tid >> 6;
    // bijective XCD swizzle over 768 blocks (768 % 8 == 0): 96 blocks per XCD
    int bid = blockIdx.x;
    int wg = (bid & 7) * 96 + (bid >> 3);
    int bx = wg % 24, by = wg / 24;          // bx: n-tile (0..23), by: m-tile (0..31)
    const int m0 = by * 128, n0 = bx * 128;
    const int wr = wid >> 2, wc = wid & 3;   // wr 0..1 (64 rows), wc 0..3 (32 cols)
    const int g = lane >> 4, r = lane & 15;
    f32x4 acc[4][2] = {};

    const unsigned short* Abase = A  + (size_t)by * 16 * 8192;
    const unsigned short* Bbase = Bt + (size_t)bx * 16 * 8192;

#define GSTAGE(kt, buf) do {                                                              \
        const unsigned short* _a = Abase + (size_t)(kt) * 8192 + tid * 8;                 \
        const unsigned short* _b = Bbase + (size_t)(kt) * 8192 + tid * 8;                 \
        __builtin_amdgcn_global_load_lds((const AS1 void*)(_a),        (AS3 void*)((char*)As[buf] + tid * 16),        16, 0, 0); \
        __builtin_amdgcn_global_load_lds((const AS1 void*)(_a + 4096), (AS3 void*)((char*)As[buf] + 8192 + tid * 16), 16, 0, 0); \
        __builtin_amdgcn_global_load_lds((const AS1 void*)(_b),        (AS3 void*)((char*)Bs[buf] + tid * 16),        16, 0, 0); \
        __builtin_amdgcn_global_load_lds((const AS1 void*)(_b + 4096), (AS3 void*)((char*)Bs[buf] + 8192 + tid * 16), 16, 0, 0); \
    } while (0)

    GSTAGE(0, 0);
    GSTAGE(1, 1);
    asm volatile("s_waitcnt vmcnt(4)" ::: "memory");   // tile0 landed; tile1 in flight
    __builtin_amdgcn_s_barrier();
    __builtin_amdgcn_sched_barrier(0);

    for (int kt = 0; kt < 16; ++kt) {
        const unsigned short* Ac = As[kt % 3];
        const unsigned short* Bc = Bs[kt % 3];
        if (kt < 14) GSTAGE(kt + 2, (kt + 2) % 3);     // distance-2 prefetch
#pragma unroll
        for (int kk = 0; kk < 2; ++kk) {
            b16x8 af[4], bfr[2];
#pragma unroll
            for (int mi = 0; mi < 4; ++mi) {
                int row = wr * 64 + mi * 16 + r;
                int e = (row * 64 + kk * 32 + g * 8) ^ ((row & 7) << 3);
                af[mi] = __builtin_bit_cast(b16x8, *(const uint4*)(Ac + e));
            }
#pragma unroll
            for (int ni = 0; ni < 2; ++ni) {
                int row = wc * 32 + ni * 16 + r;
                int e = (row * 64 + kk * 32 + g * 8) ^ ((row & 7) << 3);
                bfr[ni] = __builtin_bit_cast(b16x8, *(const uint4*)(Bc + e));
            }
#pragma unroll
            for (int mi = 0; mi < 4; ++mi)
#pragma unroll
                for (int ni = 0; ni < 2; ++ni)
                    acc[mi][ni] = __builtin_amdgcn_mfma_f32_16x16x32_bf16(af[mi], bfr[ni], acc[mi][ni], 0, 0, 0);
        }
        asm volatile("s_waitcnt lgkmcnt(0)" ::: "memory");   // my ds_reads retired
        if (kt < 15) {
            if (kt < 14) asm volatile("s_waitcnt vmcnt(4)" ::: "memory");  // next tile landed
            else         asm volatile("s_waitcnt vmcnt(0)" ::: "memory");  // last tile: drain
            __builtin_amdgcn_s_barrier();
            __builtin_amdgcn_sched_barrier(0);
        }
    }
#undef GSTAGE

    for (int ni = 0; ni < 2; ++ni) {
        int col = n0 + wc * 32 + ni * 16 + r;           // [0, 3072)
        int which = col >> 10, c = col & 1023;
        const float* bp = which == 0 ? bq : which == 1 ? bk : bv;
        float bvv = bp[c];
        int h = c >> 6, hd = c & 63;
        for (int mi = 0; mi < 4; ++mi)
            for (int j = 0; j < 4; ++j) {
                int row = m0 + wr * 64 + mi * 16 + g * 4 + j;
                float v = acc[mi][ni][j] + bvv;
                int b = row >> 11, s = row & 2047;
                size_t bh = (size_t)(b * 16 + h);
                if (which == 0) {
                    Qb[(bh * 2048 + s) * 64 + hd] = f2bf(v * 0.180336881f);  // 0.125*log2e
                } else if (which == 1) {
                    int tt = s >> 6, kr = s & 63;
                    Kt[(bh * 32 + tt) * 4096 + ((kr * 64 + hd) ^ ((kr & 7) << 3))] = f2bf(v);
                } else {
                    int tt = s >> 6, cc = s & 63;
                    Vt[(bh * 32 + tt) * 4096 + ((hd * 64 + cc) ^ ((hd & 7) << 3))] = f2bf(v);
                }
            }
    }
}

// ---------------- proj GEMM: 128x128 tile, BK=64, 3-buf counted vmcnt (R15) ----------------
// grid 256 linear, XCD-swizzled (32 blocks/XCD).  out = acc + bias + x.
__global__ __launch_bounds__(512) void k_gemm_proj(
    const unsigned short* __restrict__ A, const unsigned short* __restrict__ Bt,
    const float* __restrict__ bias, const float* __restrict__ x,
    float* __restrict__ out) {
    __shared__ unsigned short As[3][8192];   // 48 KB
    __shared__ unsigned short Bs[3][8192];   // 48 KB
    const int tid = threadIdx.x, lane = tid & 63, wid = tid >> 6;
    int bid = blockIdx.x;
    int wg = (bid & 7) * 32 + (bid >> 3);    // 256 % 8 == 0
    int bx = wg % 8, by = wg / 8;            // bx: n-tile (0..7), by: m-tile (0..31)
    const int m0 = by * 128, n0 = bx * 128;
    const int wr = wid >> 2, wc = wid & 3;
    const int g = lane >> 4, r = lane & 15;
    f32x4 acc[4][2] = {};

    const unsigned short* Abase = A  + (size_t)by * 16 * 8192;
    const unsigned short* Bbase = Bt + (size_t)bx * 16 * 8192;

#define PSTAGE(kt, buf) do {                                                              \
        const unsigned short* _a = Abase + (size_t)(kt) * 8192 + tid * 8;                 \
        const unsigned short* _b = Bbase + (size_t)(kt) * 8192 + tid * 8;                 \
        __builtin_amdgcn_global_load_lds((const AS1 void*)(_a),        (AS3 void*)((char*)As[buf] + tid * 16),        16, 0, 0); \
        __builtin_amdgcn_global_load_lds((const AS1 void*)(_a + 4096), (AS3 void*)((char*)As[buf] + 8192 + tid * 16), 16, 0, 0); \
        __builtin_amdgcn_global_load_lds((const AS1 void*)(_b),        (AS3 void*)((char*)Bs[buf] + tid * 16),        16, 0, 0); \
        __builtin_amdgcn_global_load_lds((const AS1 void*)(_b + 4096), (AS3 void*)((char*)Bs[buf] + 8192 + tid * 16), 16, 0, 0); \
    } while (0)

    PSTAGE(0, 0);
    PSTAGE(1, 1);
    asm volatile("s_waitcnt vmcnt(4)" ::: "memory");
    __builtin_amdgcn_s_barrier();
    __builtin_amdgcn_sched_barrier(0);

    for (int kt = 0; kt < 16; ++kt) {
        const unsigned short* Ac = As[kt % 3];
        const unsigned short* Bc = Bs[kt % 3];
        if (kt < 14) PSTAGE(kt + 2, (kt + 2) % 3);
#pragma unroll
        for (int kk = 0; kk < 2; ++kk) {
            b16x8 af[4], bfr[2];
#pragma unroll
            for (int mi = 0; mi < 4; ++mi) {
                int row = wr * 64 + mi * 16 + r;
                int e = (row * 64 + kk * 32 + g * 8) ^ ((row & 7) << 3);
                af[mi] = __builtin_bit_cast(b16x8, *(const uint4*)(Ac + e));
            }
#pragma unroll
            for (int ni = 0; ni < 2; ++ni) {
                int row = wc * 32 + ni * 16 + r;
                int e = (row * 64 + kk * 32 + g * 8) ^ ((row & 7) << 3);
                bfr[ni] = __builtin_bit_cast(b16x8, *(const uint4*)(Bc + e));
            }
#pragma unroll
            for (int mi = 0; mi < 4; ++mi)
#pragma unroll
                for (int ni = 0; ni < 2; ++ni)
                    acc[mi][ni] = __builtin_amdgcn_mfma_f32_16x16x32_bf16(af[mi], bfr[ni], acc[mi][ni], 0, 0, 0);
        }
        asm volatile("s_waitcnt lgkmcnt(0)" ::: "memory");
        if (kt < 15) {
            if (kt < 14) asm volatile("s_waitcnt vmcnt(4)" ::: "memory");
            else         asm volatile("s_waitcnt vmcnt(0)" ::: "memory");
            __builtin_amdgcn_s_barrier();
            __builtin_amdgcn_sched_barrier(0);
        }
    }
#undef PSTAGE

    for (int ni = 0; ni < 2; ++ni) {
        int col = n0 + wc * 32 + ni * 16 + r;
        float bv = bias[col];
        for (int mi = 0; mi < 4; ++mi)
            for (int j = 0; j < 4; ++j) {
                int row = m0 + wr * 64 + mi * 16 + g * 4 + j;
                size_t off = (size_t)row * 1024 + col;
                out[off] = acc[mi][ni][j] + bv + x[off];   // residual fused
            }
    }
}

// ---------------- flash attention: split-KV, fixed-base softmax (R15 exact) ----------------
#define TSWZ(row, byteoff) ((((row) * 128) + (byteoff)) ^ (((row) & 7) << 4))

__global__ __launch_bounds__(512, 4) void k_attn(const unsigned short* __restrict__ Qb,
                                                 const unsigned short* __restrict__ Kt,
                                                 const unsigned short* __restrict__ Vt,
                                                 unsigned short* __restrict__ ctx) {
    __shared__ unsigned short Ks[2][2][4096];   // [group][dbuf] 32 KB
    __shared__ unsigned short Vs[2][2][4096];   // 32 KB
    __shared__ float lsh[4][64];                // 1 KB (group1 l)
    const int tid = threadIdx.x, lane = tid & 63, w = tid >> 6;   // w in 0..7
    const int q32 = lane & 31, hi = lane >> 5;
    const int wq = w & 3, grp = w >> 2;
    const int lt = wq * 64 + lane;              // 0..255 within group

    int bid = blockIdx.x;
    int xcd = bid & 7, idx = bid >> 3;
    int bh = xcd * 4 + (idx & 3);               // 4 heads/XCD -> K/V L2-resident
    int q0 = (idx >> 2) * 128;
    const int b = bh >> 4, h = bh & 15;

    const unsigned short* qrow = Qb + ((size_t)bh * 2048 + q0 + wq * 32 + q32) * 64 + hi * 8;
    b16x8 qf[4];
#pragma unroll
    for (int ds = 0; ds < 4; ++ds)
        qf[ds] = __builtin_bit_cast(b16x8, *(const uint4*)(qrow + ds * 16));

    const unsigned short* Kg = Kt + (size_t)bh * 32 * 4096;
    const unsigned short* Vg = Vt + (size_t)bh * 32 * 4096;
    const int ktbase = grp * 16;

#define STAGE(i, buf) do {                                                                \
        const unsigned short* _ks = Kg + (size_t)(ktbase + (i)) * 4096 + lt * 8;          \
        const unsigned short* _vs = Vg + (size_t)(ktbase + (i)) * 4096 + lt * 8;          \
        __builtin_amdgcn_global_load_lds((const AS1 void*)_ks,          (AS3 void*)((char*)Ks[grp][buf] + lt * 16),        16, 0, 0); \
        __builtin_amdgcn_global_load_lds((const AS1 void*)(_ks + 2048), (AS3 void*)((char*)Ks[grp][buf] + 4096 + lt * 16), 16, 0, 0); \
        __builtin_amdgcn_global_load_lds((const AS1 void*)_vs,          (AS3 void*)((char*)Vs[grp][buf] + lt * 16),        16, 0, 0); \
        __builtin_amdgcn_global_load_lds((const AS1 void*)(_vs + 2048), (AS3 void*)((char*)Vs[grp][buf] + 4096 + lt * 16), 16, 0, 0); \
    } while (0)

    float lpart = 0.f;
    f32x16 oacc[2] = {};

    STAGE(0, 0);
    __syncthreads();

    for (int i = 0; i < 16; ++i) {
        const int cur = i & 1;
        if (i < 15) STAGE(i + 1, cur ^ 1);      // async prefetch, drained at barrier

        f32x16 sacc[2] = {};
#pragma unroll
        for (int ds = 0; ds < 4; ++ds) {
            b16x8 kf0 = __builtin_bit_cast(b16x8, *(const uint4*)((char*)Ks[grp][cur] + TSWZ(q32,      ds * 32 + hi * 16)));
            b16x8 kf1 = __builtin_bit_cast(b16x8, *(const uint4*)((char*)Ks[grp][cur] + TSWZ(32 + q32, ds * 32 + hi * 16)));
            sacc[0] = __builtin_amdgcn_mfma_f32_32x32x16_bf16(kf0, qf[ds], sacc[0], 0, 0, 0);
            sacc[1] = __builtin_amdgcn_mfma_f32_32x32x16_bf16(kf1, qf[ds], sacc[1], 0, 0, 0);
        }

        // fixed-base softmax: P = 2^s (scores bounded; shift-invariant; l divides out)
        float pb[2][16];
#pragma unroll
        for (int kb = 0; kb < 2; ++kb)
#pragma unroll
            for (int reg = 0; reg < 16; ++reg)
                pb[kb][reg] = exp2_fast(sacc[kb][reg]);
        {   // balanced-tree sum
            float t0 = (pb[0][0]  + pb[0][1])  + (pb[0][2]  + pb[0][3]);
            float t1 = (pb[0][4]  + pb[0][5])  + (pb[0][6]  + pb[0][7]);
            float t2 = (pb[0][8]  + pb[0][9])  + (pb[0][10] + pb[0][11]);
            float t3 = (pb[0][12] + pb[0][13]) + (pb[0][14] + pb[0][15]);
            float t4 = (pb[1][0]  + pb[1][1])  + (pb[1][2]  + pb[1][3]);
            float t5 = (pb[1][4]  + pb[1][5])  + (pb[1][6]  + pb[1][7]);
            float t6 = (pb[1][8]  + pb[1][9])  + (pb[1][10] + pb[1][11]);
            float t7 = (pb[1][12] + pb[1][13]) + (pb[1][14] + pb[1][15]);
            lpart += ((t0 + t1) + (t2 + t3)) + ((t4 + t5) + (t6 + t7));
        }
        unsigned wv[2][4][2];
#pragma unroll
        for (int kb = 0; kb < 2; ++kb)
#pragma unroll
            for (int rg = 0; rg < 4; ++rg) {
                wv[kb][rg][0] = cvt_pk_bf16(pb[kb][rg * 4 + 0], pb[kb][rg * 4 + 1]);
                wv[kb][rg][1] = cvt_pk_bf16(pb[kb][rg * 4 + 2], pb[kb][rg * 4 + 3]);
            }
        b16x8 pa[4];
#pragma unroll
        for (int ks = 0; ks < 4; ++ks) {
            int kb = ks >> 1, rg0 = (ks & 1) * 2;
            unsigned u0 = wv[kb][rg0][0], u2 = wv[kb][rg0 + 1][0];
            permswap(u0, u2);
            unsigned u1 = wv[kb][rg0][1], u3 = wv[kb][rg0 + 1][1];
            permswap(u1, u3);
            uint4 uu; uu.x = u0; uu.y = u1; uu.z = u2; uu.w = u3;
            pa[ks] = __builtin_bit_cast(b16x8, uu);
        }
#pragma unroll
        for (int ks = 0; ks < 4; ++ks) {
            b16x8 vf0 = __builtin_bit_cast(b16x8, *(const uint4*)((char*)Vs[grp][cur] + TSWZ(q32,      ks * 32 + hi * 16)));
            b16x8 vf1 = __builtin_bit_cast(b16x8, *(const uint4*)((char*)Vs[grp][cur] + TSWZ(32 + q32, ks * 32 + hi * 16)));
            oacc[0] = __builtin_amdgcn_mfma_f32_32x32x16_bf16(pa[ks], vf0, oacc[0], 0, 0, 0);
            oacc[1] = __builtin_amdgcn_mfma_f32_32x32x16_bf16(pa[ks], vf1, oacc[1], 0, 0, 0);
        }
        __syncthreads();
    }

    {
        unsigned a = __builtin_bit_cast(unsigned, lpart), bb = a;
        permswap(a, bb);
        lpart = __builtin_bit_cast(float, a) + __builtin_bit_cast(float, bb);
    }

    float* s0 = (float*)Ks[1];
    float* s1 = (float*)Vs[1];
    if (grp == 1) {
        int base = (wq * 64 + lane) * 16;
#pragma unroll
        for (int reg = 0; reg < 16; ++reg) {
            s0[base + reg] = oacc[0][reg];
            s1[base + reg] = oacc[1][reg];
        }
        lsh[wq][lane] = lpart;
    }
    __syncthreads();
    if (grp == 0) {
        float l = lpart + lsh[wq][lane];
        float inv = 1.f / l;
        int base = (wq * 64 + lane) * 16;
#pragma unroll
        for (int reg = 0; reg < 16; ++reg) {
            int qr = (reg & 3) + 8 * (reg >> 2) + 4 * hi;
            float iv = __shfl(inv, qr, 64);
            float o0 = (oacc[0][reg] + s0[base + reg]) * iv;
            float o1 = (oacc[1][reg] + s1[base + reg]) * iv;
            // ctx tiled+swizzled [rt][kt=h][128x64]
            int row = b * 2048 + q0 + wq * 32 + qr;
            int rt = row >> 7, rr = row & 127;
            size_t tbase = (size_t)(rt * 16 + h) * 8192;
            ctx[tbase + ((rr * 64 + q32)      ^ ((rr & 7) << 3))] = f2bf(o0);
            ctx[tbase + ((rr * 64 + q32 + 32) ^ ((rr & 7) << 3))] = f2bf(o1);
        }
    }
#undef STAGE
}

// ---------------- LayerNorm (residual already fused into proj): one wave per row ----------------
__global__ __launch_bounds__(256) void k_ln(const float* __restrict__ yin,
                                            const float* __restrict__ gamma,
                                            const float* __restrict__ beta,
                                            float* __restrict__ out) {
    int t = threadIdx.x, lane = t & 63, w = t >> 6;
    int row = blockIdx.x * 4 + w;
    const float4* yr = (const float4*)(yin + (size_t)row * 1024);
    float4 y[4];
    float s = 0.f, ss = 0.f;
#pragma unroll
    for (int i = 0; i < 4; ++i) {
        float4 yy = yr[lane + i * 64];
        y[i] = yy;
        s  += yy.x + yy.y + yy.z + yy.w;
        ss += yy.x * yy.x + yy.y * yy.y + yy.z * yy.z + yy.w * yy.w;
    }
#pragma unroll
    for (int o = 32; o > 0; o >>= 1) {
        s  += __shfl_xor(s,  o, 64);
        ss += __shfl_xor(ss, o, 64);
    }
    float mu  = s * (1.f / 1024.f);
    float var = ss * (1.f / 1024.f) - mu * mu;
    float inv = rsqrtf(var + 1e-5f);
    float4* outr = (float4*)(out + (size_t)row * 1024);
    const float4* gr = (const float4*)gamma;
    const float4* br = (const float4*)beta;
#pragma unroll
    for (int i = 0; i < 4; ++i) {
        float4 g4 = gr[lane + i * 64], b4 = br[lane + i * 64];
        float4 o4;
        o4.x = (y[i].x - mu) * inv * g4.x + b4.x;
        o4.y = (y[i].y - mu) * inv * g4.y + b4.y;
        o4.z = (y[i].z - mu) * inv * g4.z + b4.z;
        o4.w = (y[i].w - mu) * inv * g4.w + b4.w;
        outr[lane + i * 64] = o4;
    }
}

// ---------------------------------------------------------------------------
extern "C" void kernel_launch(void* const* d_in, const int* in_sizes, int n_in,
                              void* d_out, int out_size, void* d_ws, size_t ws_size,
                              hipStream_t stream) {
    const float* x  = (const float*)d_in[0];
    const float* Wq = (const float*)d_in[1];
    const float* bq = (const float*)d_in[2];
    const float* Wk = (const float*)d_in[3];
    const float* bk = (const float*)d_in[4];
    const float* Wv = (const float*)d_in[5];
    const float* bv = (const float*)d_in[6];
    const float* Wo = (const float*)d_in[7];
    const float* bo = (const float*)d_in[8];
    const float* gamma = (const float*)d_in[9];
    const float* beta  = (const float*)d_in[10];

    char* ws = (char*)d_ws;
    const size_t MB = 1u << 20;
    unsigned short* xbf   = (unsigned short*)(ws);            // 8 MiB tiled; reused as ctx (tiled)
    unsigned short* Wqkvt = (unsigned short*)(ws + 8 * MB);   // 6 MiB tiled [24][16][8192]
    unsigned short* Wot   = (unsigned short*)(ws + 14 * MB);  // 2 MiB tiled [8][16][8192]
    unsigned short* Qb    = (unsigned short*)(ws + 16 * MB);  // 8 MiB
    unsigned short* Kt    = (unsigned short*)(ws + 24 * MB);  // 8 MiB (swz tiles)
    unsigned short* Vt    = (unsigned short*)(ws + 32 * MB);  // 8 MiB (swz tiles)
    float* proj = (float*)(ws + 16 * MB);                     // 16 MiB, overlays Qb+Kt (dead by then)
    unsigned short* ctx = xbf;                                // overlays xbf (dead after qkv)

    k_cvt_x<<<2048, 256, 0, stream>>>(x, xbf);
    k_cvt_w<<<dim3(32, 32, 4), dim3(32, 32), 0, stream>>>(
        Wq, Wk, Wv, Wo, Wqkvt, Wqkvt + 1024 * 1024, Wqkvt + 2 * 1024 * 1024, Wot);
    k_gemm_qkv<<<768, 512, 0, stream>>>(xbf, Wqkvt, bq, bk, bv, Qb, Kt, Vt);
    k_attn<<<512, 512, 0, stream>>>(Qb, Kt, Vt, ctx);
    k_gemm_proj<<<256, 512, 0, stream>>>(ctx, Wot, bo, x, proj);
    k_ln<<<1024, 256, 0, stream>>>(proj, gamma, beta, (float*)d_out);
}